// Round 10
// baseline (1467.343 us; speedup 1.0000x reference)
//
#include <hip/hip_runtime.h>

// VQProsodyEncoder on gfx950: 13x conv1d(K=5) as implicit-GEMM f16 MFMA,
// fused maxpool(8), VQ via (-2*z.c + |c|^2) GEMM + fused argmin + gather.
// Activations: channel-last f16 [B][T+4][C] with 2-row zero halos.
// R11 = R7's verified conv core (112us big-conv, 0 bank conflicts) + launch-
// structure overhaul: measured ~480us outside the 6 big convs vs ~180us of
// modeled work -> dispatch boundaries + latency-bound tail kernels dominate.
//  (1) prep: halo+4 repacks+cb+mel merged into one kernel (7 launches -> 1)
//  (2) maxpool fused into stack-1 conv #6 epilogue (shfl-max, pooled write)
//  (3) tail_fused: 6 stack-2 convs + post-conv + VQ GEMM in ONE persistent
//      192-block kernel (co-resident at 3 blk/CU cap) with device-scope
//      atomic grid barriers; weights/activations stay L2-hot.
//  (4) vq_gather: wave-per-row, shfl argmin of the 8 tile partials.
// Launches: 23 -> 11.

typedef _Float16 f16;
typedef __attribute__((ext_vector_type(8))) _Float16 half8;
typedef __attribute__((ext_vector_type(4))) _Float16 half4;
typedef __attribute__((ext_vector_type(4))) float float4v;

__device__ __forceinline__ void async16(const void* g, void* l) {
  __builtin_amdgcn_global_load_lds(
      (const __attribute__((address_space(1))) void*)g,
      (__attribute__((address_space(3))) void*)l, 16, 0, 0);
}

// device-scope grid barrier: __syncthreads drains each wave's stores (vmcnt0
// before s_barrier), thread0 release-adds (L2 writeback at agent scope) and
// acquire-spins (L1 inv). All 192 blocks always execute every barrier.
__device__ __forceinline__ void grid_bar(int* bar, int tgt) {
  __syncthreads();
  if (threadIdx.x == 0) {
    __threadfence();
    __hip_atomic_fetch_add(bar, 1, __ATOMIC_ACQ_REL, __HIP_MEMORY_SCOPE_AGENT);
    while (__hip_atomic_load(bar, __ATOMIC_ACQUIRE,
                             __HIP_MEMORY_SCOPE_AGENT) < tgt)
      __builtin_amdgcn_s_sleep(8);
  }
  __syncthreads();
  __threadfence();
}

// ---------------------------------------------------------------------------
// conv tile as implicit GEMM: Y[b,t,o] = sum_{kt,ci} W[kt][o][ci]*X[b][t+kt-2][ci]
// tile 128(M=o) x 128(N=b*t), BK=32, 4 waves 64x64, mfma_f32_16x16x32_f16.
// Wf fragment-major: [NTAP][Cinp/32][Cout/16][64 lanes][8 f16]. (R7-verified.)
template <int NTAP>
__device__ void conv_tile(
    const f16* __restrict__ Xb, const f16* __restrict__ Wf,
    const float* __restrict__ bias, const f16* __restrict__ Res,
    float* __restrict__ Yf, f16* __restrict__ Yb, f16* __restrict__ Pool,
    float2* __restrict__ Pmin, int pstride,
    int Cinp, int Cout, int lgT, int tapshift, int relu,
    int n0, int o0, int py, f16* Als, f16* Bls)
{
  const int tid  = threadIdx.x;
  const int wave = tid >> 6;
  const int lane = tid & 63;
  const int T  = 1 << lgT;
  const int b  = n0 >> lgT;
  const int t0 = n0 & (T - 1);

  const int lane4 = lane >> 2;  // row-within-16 for B staging
  // B pre-swizzle (both-sides): phys slot (lane&3) of LDS row r*16+lane4
  // holds global slot (lane&3)^((row>>1)&3) == (lane&3)^((lane>>3)&3).
  const int lkB = ((lane & 3) ^ ((lane >> 3) & 3)) << 3;
  const f16* gB0 = Xb + (size_t)(b * (T + 4) + t0) * Cinp + lkB;

  const int mB  = (wave & 1) * 64;
  const int nB  = (wave >> 1) * 64;
  const int r16 = lane & 15;
  const int g4  = lane >> 4;
  const int C32 = Cinp >> 5;
  const int OB  = Cout >> 4;
  const int fb  = (wave & 1) * 4;

  const f16* gW = Wf + (((size_t)(o0 >> 4)) << 9) + lane * 8;

  float4v acc[4][4] = {};

#pragma unroll 1
  for (int c32 = 0; c32 < C32; ++c32) {
    __syncthreads();  // previous iteration's LDS reads complete
#pragma unroll
    for (int r = wave; r < NTAP * 8; r += 4) {
      const int kt = r >> 3, frag = r & 7;
      async16(gW + (((size_t)((kt * C32 + c32) * OB) + frag) << 9),
              &Als[r * 512 + lane * 8]);
    }
    for (int r = wave; r < 9; r += 4)
      async16(gB0 + (size_t)(r * 16 + lane4) * Cinp + (c32 << 5),
              &Bls[r * 512 + lane * 8]);
    __syncthreads();  // drains vmcnt: staging visible

#pragma unroll
    for (int kt = 0; kt < NTAP; ++kt) {
      half8 af[4], bv[4];
#pragma unroll
      for (int i = 0; i < 4; ++i)
        af[i] = *(const half8*)&Als[(kt * 8 + fb + i) * 512 + lane * 8];
#pragma unroll
      for (int j = 0; j < 4; ++j) {
        const int row = nB + j * 16 + r16 + tapshift + kt;
        const int sl  = g4 ^ ((row >> 1) & 3);
        bv[j] = *(const half8*)&Bls[row * 32 + sl * 8];
      }
      __builtin_amdgcn_s_setprio(1);
#pragma unroll
      for (int i = 0; i < 4; ++i)
#pragma unroll
        for (int j = 0; j < 4; ++j)
          acc[i][j] = __builtin_amdgcn_mfma_f32_16x16x32_f16(af[i], bv[j], acc[i][j], 0, 0, 0);
      __builtin_amdgcn_s_setprio(0);
    }
  }

  // epilogue: D[row][col]: col = lane&15, row = (lane>>4)*4 + reg
  const int col = lane & 15;
  const int qr4 = (lane >> 4) << 2;

  if (Pmin) {
    // VQ: per-row argmin over this tile's 128 bins -> Pmin[n][pstride]
    float bv[4] = {3.4e38f, 3.4e38f, 3.4e38f, 3.4e38f};
    int   bi[4] = {0, 0, 0, 0};
#pragma unroll
    for (int i = 0; i < 4; ++i) {
      const int o = o0 + mB + i * 16 + qr4;
      const float4v bb = *(const float4v*)&bias[o];  // |c|^2
#pragma unroll
      for (int j = 0; j < 4; ++j) {
        float4v v = acc[i][j] + bb;
#pragma unroll
        for (int r = 0; r < 4; ++r) {
          const float f = v[r];
          const int id = o + r;
          if (f < bv[j] || (f == bv[j] && id < bi[j])) { bv[j] = f; bi[j] = id; }
        }
      }
    }
#pragma unroll
    for (int off = 32; off >= 16; off >>= 1)
#pragma unroll
      for (int j = 0; j < 4; ++j) {
        const float ov = __shfl_down(bv[j], off);
        const int   oi = __shfl_down(bi[j], off);
        if (ov < bv[j] || (ov == bv[j] && oi < bi[j])) { bv[j] = ov; bi[j] = oi; }
      }
    __syncthreads();  // LDS reads done -> reuse Als as candidate scratch
    float2* cand = (float2*)Als;  // [128 t][2 m-waves]
    if (lane < 16)
#pragma unroll
      for (int j = 0; j < 4; ++j)
        cand[(nB + j * 16 + lane) * 2 + (wave & 1)] =
            make_float2(bv[j], __int_as_float(bi[j]));
    __syncthreads();
    if (tid < 128) {
      float2 c0 = cand[tid * 2 + 0], c1 = cand[tid * 2 + 1];
      int i0 = __float_as_int(c0.x < c1.x ? c0.y : c1.y);
      float v0 = fminf(c0.x, c1.x);
      if (c0.x == c1.x) i0 = min(__float_as_int(c0.y), __float_as_int(c1.y));
      Pmin[(size_t)(n0 + tid) * pstride + py] =
          make_float2(v0, __int_as_float(i0));
    }
    return;
  }

  if (Pool) {
    // fused maxpool(8) over t: 8-lane shfl-max, write pooled rows only.
    const int TP4 = (T >> 3) + 4;  // pooled buffer rows incl. halo
#pragma unroll
    for (int i = 0; i < 4; ++i) {
      const int o = o0 + mB + i * 16 + qr4;
      const float4v bb = *(const float4v*)&bias[o];
#pragma unroll
      for (int j = 0; j < 4; ++j) {
        const int t = t0 + nB + j * 16 + col;
        float4v v = acc[i][j] + bb;
        if (relu) {
          v.x = fmaxf(v.x, 0.f); v.y = fmaxf(v.y, 0.f);
          v.z = fmaxf(v.z, 0.f); v.w = fmaxf(v.w, 0.f);
        }
        if (Res) {
          half4 r = *(const half4*)&Res[(size_t)(b * (T + 4) + t + 2) * Cout + o];
          v.x += (float)r.x; v.y += (float)r.y; v.z += (float)r.z; v.w += (float)r.w;
        }
#pragma unroll
        for (int s = 1; s < 8; s <<= 1) {
          v.x = fmaxf(v.x, __shfl_xor(v.x, s));
          v.y = fmaxf(v.y, __shfl_xor(v.y, s));
          v.z = fmaxf(v.z, __shfl_xor(v.z, s));
          v.w = fmaxf(v.w, __shfl_xor(v.w, s));
        }
        if ((col & 7) == 0) {
          const int tp = t >> 3;
          half4 h;
          h.x = (f16)v.x; h.y = (f16)v.y; h.z = (f16)v.z; h.w = (f16)v.w;
          *(half4*)&Pool[((size_t)(b * TP4 + tp + 2)) * Cout + o] = h;
        }
      }
    }
    return;
  }

#pragma unroll
  for (int i = 0; i < 4; ++i) {
    const int o = o0 + mB + i * 16 + qr4;
    const float4v bb = *(const float4v*)&bias[o];
#pragma unroll
    for (int j = 0; j < 4; ++j) {
      const int t = t0 + nB + j * 16 + col;
      float4v v = acc[i][j] + bb;
      if (relu) {
        v.x = fmaxf(v.x, 0.f); v.y = fmaxf(v.y, 0.f);
        v.z = fmaxf(v.z, 0.f); v.w = fmaxf(v.w, 0.f);
      }
      if (Res) {
        half4 r = *(const half4*)&Res[(size_t)(b * (T + 4) + t + 2) * Cout + o];
        v.x += (float)r.x; v.y += (float)r.y; v.z += (float)r.z; v.w += (float)r.w;
      }
      if (Yf) *(float4v*)&Yf[(size_t)(b * T + t) * Cout + o] = v;
      if (Yb) {
        half4 h;
        h.x = (f16)v.x; h.y = (f16)v.y; h.z = (f16)v.z; h.w = (f16)v.w;
        *(half4*)&Yb[(size_t)(b * (T + 4) + t + 2) * Cout + o] = h;
      }
    }
  }
}

// standalone conv (pre-conv + stack-1)
template <int NTAP>
__global__ __launch_bounds__(256, 3) void conv_gemm(
    const f16* __restrict__ Xb, const f16* __restrict__ Wf,
    const float* __restrict__ bias, const f16* __restrict__ Res,
    float* __restrict__ Yf, f16* __restrict__ Yb, f16* __restrict__ Pool,
    int Cinp, int Cout, int lgT, int tapshift, int relu)
{
  __shared__ __align__(16) f16 Als[NTAP * 8 * 512];
  __shared__ __align__(16) f16 Bls[144 * 32];
  conv_tile<NTAP>(Xb, Wf, bias, Res, Yf, Yb, Pool, nullptr, 0,
                  Cinp, Cout, lgT, tapshift, relu,
                  (int)(blockIdx.x << 7), (int)(blockIdx.y << 7), 0,
                  Als, Bls);
}

// persistent tail: 6 stack-2 res convs + post-conv + VQ scores, one launch.
// 192 blocks (64 n-tiles x 3 o-tiles), co-resident (cap 3/CU * 256 CU).
__global__ __launch_bounds__(256, 3) void tail_fused(
    f16* xb0, f16* xb1, const f16* __restrict__ wpB2,
    const float* __restrict__ b_b2, const f16* __restrict__ wpPost,
    const float* __restrict__ b_post, float* __restrict__ zf,
    f16* __restrict__ zeb, const f16* __restrict__ wpCb,
    const float* __restrict__ cnorm, float2* __restrict__ part, int* bar)
{
  __shared__ __align__(16) f16 Als[5 * 8 * 512];
  __shared__ __align__(16) f16 Bls[144 * 32];
  const int bid = blockIdx.x;
  const int n0 = (bid & 63) << 7;
  const int o0 = (bid >> 6) << 7;
  int use = 0;
  // 6 residual conv blocks @ T=256
  for (int l = 0; l < 6; ++l) {
    f16* in  = (l & 1) ? xb1 : xb0;
    f16* out = (l & 1) ? xb0 : xb1;
    conv_tile<5>(in, wpB2 + (size_t)l * 5 * 384 * 384, b_b2 + l * 384, in,
                 nullptr, out, nullptr, nullptr, 0,
                 384, 384, 8, 0, 1, n0, o0, 0, Als, Bls);
    grid_bar(bar, 192 * (++use));
  }
  // post-conv: 128 tiles (64 n x 2 o); blocks >=128 idle but join barrier
  if (bid < 128)
    conv_tile<5>(xb0, wpPost, b_post, nullptr, zf, zeb, nullptr, nullptr, 0,
                 384, 256, 8, 0, 0, n0, (bid >> 6) << 7, 0, Als, Bls);
  grid_bar(bar, 192 * (++use));
  // VQ scores + per-tile argmin: 512 tiles (64 n x 8 o)
  for (int t = bid; t < 512; t += 192)
    conv_tile<1>(zeb, wpCb, cnorm, nullptr, nullptr, nullptr, nullptr, part, 8,
                 256, 1024, 8, 2, 0, (t & 63) << 7, (t >> 6) << 7, t >> 6,
                 Als, Bls);
}

// ---------------------------------------------------------------------------
// merged preprocessing: halo zero + weight repacks + codebook + mel cast.
__device__ void repack_dev(const float* __restrict__ w, f16* __restrict__ wp,
                           int O, int I, int Ip, int l, int xb, int nxb)
{
  const int C8 = Ip >> 3;
  const int n = O * C8;
  const float* wl = w + (size_t)l * O * I * 5;
  f16* wpl = wp + (size_t)l * 5 * O * Ip;
  const int OB = O >> 4;
  for (int e = xb * 256 + threadIdx.x; e < n; e += nxb * 256) {
    const int o = e / C8, c8 = e - o * C8;
    const int ci0 = c8 << 3;
    const size_t base = ((((size_t)(ci0 >> 5) * OB + (o >> 4)) << 6)
                         + ((o & 15) | ((c8 & 3) << 4))) << 3;
    half8 hv[5];
#pragma unroll
    for (int kt = 0; kt < 5; ++kt)
#pragma unroll
      for (int u = 0; u < 8; ++u) hv[kt][u] = (f16)0.f;
    const int lim = (I - ci0 < 8) ? (I - ci0) : 8;
    for (int u = 0; u < lim; ++u) {
      const float* src = wl + ((size_t)o * I + ci0 + u) * 5;
#pragma unroll
      for (int kt = 0; kt < 5; ++kt) hv[kt][u] = (f16)src[kt];
    }
#pragma unroll
    for (int kt = 0; kt < 5; ++kt)
      *(half8*)&wpl[(size_t)kt * O * Ip + base] = hv[kt];
  }
}

__global__ void prep(const float* __restrict__ w_pre,
                     const float* __restrict__ w_b1,
                     const float* __restrict__ w_b2,
                     const float* __restrict__ w_post,
                     const float* __restrict__ cbk,
                     const float* __restrict__ mel,
                     f16* wpPre, f16* wpB1, f16* wpB2, f16* wpPost,
                     f16* wpCb, float* cnorm, f16* xmel,
                     f16* a0, f16* a1, f16* b0, f16* b1, f16* zb,
                     float* accum, int* bar)
{
  const int bid = blockIdx.x;
  const int tid = threadIdx.x;
  if (bid == 0 && tid == 0) { accum[0] = 0.f; accum[1] = 0.f; *bar = 0; }

  if (bid < 640) {                       // halo zero: 5 bufs * 32 b * 4 rows
    int buf = bid >> 7, r = bid & 127, bb = r >> 2, k = r & 3;
    f16* p; int T4, C;
    if      (buf == 0) { p = a0; T4 = 2052; C = 384; }
    else if (buf == 1) { p = a1; T4 = 2052; C = 384; }
    else if (buf == 2) { p = b0; T4 = 260;  C = 384; }
    else if (buf == 3) { p = b1; T4 = 260;  C = 384; }
    else               { p = zb; T4 = 260;  C = 256; }
    int tt = (k < 2) ? k : (T4 - 4 + k);
    f16* rowp = p + ((size_t)bb * T4 + tt) * C;
    for (int c = tid; c < C; c += 256) rowp[c] = (f16)0.f;
  } else if (bid < 1072) {               // B1 repack: 72 x 6 layers
    repack_dev(w_b1, wpB1, 384, 384, 384, (bid - 640) / 72, (bid - 640) % 72, 72);
  } else if (bid < 1504) {               // B2 repack
    repack_dev(w_b2, wpB2, 384, 384, 384, (bid - 1072) / 72, (bid - 1072) % 72, 72);
  } else if (bid < 1522) {               // pre repack: 18 blocks
    repack_dev(w_pre, wpPre, 384, 80, 96, 0, bid - 1504, 18);
  } else if (bid < 1570) {               // post repack: 48 blocks
    repack_dev(w_post, wpPost, 256, 384, 384, 0, bid - 1522, 48);
  } else if (bid < 1826) {               // codebook: 4 rows/block (wave each)
    int o = (bid - 1570) * 4 + (tid >> 6);
    int lane = tid & 63;
    float4v c = *(const float4v*)&cbk[(size_t)o * 256 + lane * 4];
    float s = c.x * c.x + c.y * c.y + c.z * c.z + c.w * c.w;
    for (int off = 32; off > 0; off >>= 1) s += __shfl_down(s, off);
    if (lane == 0) cnorm[o] = s;
#pragma unroll
    for (int u = 0; u < 4; ++u) {
      int ci  = lane * 4 + u;
      int c32 = ci >> 5;
      int fl  = (o & 15) + (((ci >> 3) & 3) << 4);
      int e   = ci & 7;
      wpCb[(((size_t)(c32 * 64 + (o >> 4)) << 6) + fl) * 8 + e] =
          (f16)(-2.f * c[u]);
    }
  } else {                               // mel -> f16 halo'd: 3078 blocks
    int idx = (bid - 1826) * 256 + tid;
    if (idx >= 32 * 2052 * 12) return;
    int c8 = idx % 12, r = idx / 12, tt = r % 2052, b = r / 2052;
    int t = tt - 2;
    bool trow = (t >= 0) && (t < 2048);
    half8 hv;
#pragma unroll
    for (int e = 0; e < 8; ++e) {
      int m = c8 * 8 + e;
      float v = (trow && m < 80) ? mel[((size_t)b * 2048 + t) * 80 + m] : 0.f;
      hv[e] = (f16)v;
    }
    *(half8*)&xmel[((size_t)b * 2052 + tt) * 96 + c8 * 8] = hv;
  }
}

__global__ void vq_gather(const float* __restrict__ zf,   // [8192][256]
                          const float* __restrict__ cb,   // [1024][256]
                          const float2* __restrict__ P,   // [8192][8]
                          float* __restrict__ zq,
                          float* __restrict__ accum)
{
  int row = blockIdx.x * 4 + (threadIdx.x >> 6);
  int lane = threadIdx.x & 63;
  float2 p = P[(size_t)row * 8 + (lane & 7)];
  float bv = p.x;
  int j = __float_as_int(p.y);
#pragma unroll
  for (int s = 1; s < 8; s <<= 1) {
    float ov = __shfl_xor(bv, s);
    int oi = __shfl_xor(j, s);
    if (ov < bv || (ov == bv && oi < j)) { bv = ov; j = oi; }
  }
  float4v z = *(const float4v*)&zf[(size_t)row * 256 + lane * 4];
  float4v q = *(const float4v*)&cb[(size_t)j * 256 + lane * 4];
  *(float4v*)&zq[(size_t)row * 256 + lane * 4] = q;
  float4v d = z - q;
  float s = d.x * d.x + d.y * d.y + d.z * d.z + d.w * d.w;
  for (int off = 32; off > 0; off >>= 1) s += __shfl_down(s, off);
  if (lane == 0) atomicAdd(accum, s);
}

__global__ void finalize_loss(const float* __restrict__ accum,
                              float* __restrict__ out2)
{
  float c = accum[0] * (1.0f / 2097152.0f);  // mean over 32*256*256
  out2[0] = c;
  out2[1] = c;
}

// ---------------------------------------------------------------------------
extern "C" void kernel_launch(void* const* d_in, const int* in_sizes, int n_in,
                              void* d_out, int out_size, void* d_ws, size_t ws_size,
                              hipStream_t stream)
{
  (void)in_sizes; (void)n_in; (void)out_size;
  const float* mel    = (const float*)d_in[0];
  const float* w_pre  = (const float*)d_in[1];
  const float* b_pre  = (const float*)d_in[2];
  const float* w_b1   = (const float*)d_in[3];
  const float* b_b1   = (const float*)d_in[4];
  const float* w_b2   = (const float*)d_in[5];
  const float* b_b2   = (const float*)d_in[6];
  const float* w_post = (const float*)d_in[7];
  const float* b_post = (const float*)d_in[8];
  const float* cbk    = (const float*)d_in[9];
  float* out = (float*)d_out;

  size_t off = 0;
  auto carve = [&](size_t bytes) -> char* {
    char* p = (char*)d_ws + off;
    off += (bytes + 255) & ~(size_t)255;
    return p;
  };
  f16*   wpPre  = (f16*)carve((size_t)5 * 384 * 96 * 2);
  f16*   wpB1   = (f16*)carve((size_t)6 * 5 * 384 * 384 * 2);
  f16*   wpB2   = (f16*)carve((size_t)6 * 5 * 384 * 384 * 2);
  f16*   wpPost = (f16*)carve((size_t)5 * 256 * 384 * 2);
  f16*   wpCb   = (f16*)carve((size_t)1024 * 256 * 2);
  float* cnorm  = (float*)carve(1024 * 4);
  float* accum  = (float*)carve(256);
  int*   bar    = (int*)carve(256);
  f16*   xmel   = (f16*)carve((size_t)32 * 2052 * 96 * 2);
  f16*   xa0    = (f16*)carve((size_t)32 * 2052 * 384 * 2);
  f16*   xa1    = (f16*)carve((size_t)32 * 2052 * 384 * 2);
  f16*   xb0    = (f16*)carve((size_t)32 * 260 * 384 * 2);
  f16*   xb1    = (f16*)carve((size_t)32 * 260 * 384 * 2);
  f16*   zeb    = (f16*)carve((size_t)32 * 260 * 256 * 2);
  float* zf     = (float*)carve((size_t)32 * 256 * 256 * 4);
  float2* part  = (float2*)carve((size_t)8192 * 8 * 8);
  carve(131072);  // guard: B staging over-reads past last buffer
  if (off > ws_size) return;  // ~152 MB needed

  prep<<<4904, 256, 0, stream>>>(w_pre, w_b1, w_b2, w_post, cbk, mel,
                                 wpPre, wpB1, wpB2, wpPost, wpCb, cnorm, xmel,
                                 xa0, xa1, xb0, xb1, zeb, accum, bar);

  auto conv5 = [&](const f16* X, const f16* W, const float* bia, const f16* R,
                   float* YF, f16* YB, f16* PL, int Cinp, int Cout, int lgT,
                   int relu) {
    dim3 g((32 << lgT) >> 7, Cout >> 7);
    conv_gemm<5><<<g, 256, 0, stream>>>(X, W, bia, R, YF, YB, PL,
                                        Cinp, Cout, lgT, 0, relu);
  };

  // pre-conv: relu(conv(mel))
  conv5(xmel, wpPre, b_pre, nullptr, nullptr, xa0, nullptr, 96, 384, 11, 1);
  // stack 1 @ T=2048 (last layer fuses maxpool(8) -> xb0)
  for (int i = 0; i < 5; ++i) {
    f16* in = (i & 1) ? xa1 : xa0;
    f16* o_ = (i & 1) ? xa0 : xa1;
    conv5(in, wpB1 + (size_t)i * 5 * 384 * 384, b_b1 + i * 384, in,
          nullptr, o_, nullptr, 384, 384, 11, 1);
  }
  conv5(xa1, wpB1 + (size_t)5 * 5 * 384 * 384, b_b1 + 5 * 384, xa1,
        nullptr, nullptr, xb0, 384, 384, 11, 1);
  // persistent tail: stack-2 x6 + post-conv + VQ scores/argmin partials
  tail_fused<<<192, 256, 0, stream>>>(xb0, xb1, wpB2, b_b2, wpPost, b_post,
                                      zf, zeb, wpCb, cnorm, part, bar);

  vq_gather<<<2048, 256, 0, stream>>>(zf, cbk, part, out, accum);
  finalize_loss<<<1, 1, 0, stream>>>(accum, out + 2097152);
}

// Round 11
// 1161.892 us; speedup vs baseline: 1.2629x; 1.2629x over previous
//
#include <hip/hip_runtime.h>

// VQProsodyEncoder on gfx950: 13x conv1d(K=5) as implicit-GEMM f16 MFMA,
// fused maxpool(8), VQ via (-2*z.c + |c|^2) GEMM + fused argmin + gather.
// Activations: channel-last f16 [B][T+4][C] with 2-row zero halos.
// R12 = best-known conv pipeline (R7: 128x128 tile, frag-major A in LDS,
// XOR-swizzled B, 0 bank conflicts, fused VQ argmin; separate stack-2
// launches -- R11's persistent tail_fused REVERTED: its grid-barrier
// __threadfence L2 flushes cost 425us, 145MB writes) + three SAFE launch
// reductions: (1) prep merges halo+repacks+codebook+mel (7->1 launches),
// (2) maxpool fused into stack-1 conv #6 epilogue (kills kernel + 50MB
// full-res write), (3) finalize folded into vq_gather via last-block-done
// counter (release/acquire, no fences). Dispatches 25 -> 16.

typedef _Float16 f16;
typedef __attribute__((ext_vector_type(8))) _Float16 half8;
typedef __attribute__((ext_vector_type(4))) _Float16 half4;
typedef __attribute__((ext_vector_type(4))) float float4v;

__device__ __forceinline__ void async16(const void* g, void* l) {
  __builtin_amdgcn_global_load_lds(
      (const __attribute__((address_space(1))) void*)g,
      (__attribute__((address_space(3))) void*)l, 16, 0, 0);
}

// ---------------------------------------------------------------------------
// conv tile as implicit GEMM: Y[b,t,o] = sum_{kt,ci} W[kt][o][ci]*X[b][t+kt-2][ci]
// tile 128(M=o) x 128(N=b*t), BK=32, 4 waves 64x64, mfma_f32_16x16x32_f16.
// Wf fragment-major: [NTAP][Cinp/32][Cout/16][64 lanes][8 f16]. (R7-verified.)
template <int NTAP>
__device__ void conv_tile(
    const f16* __restrict__ Xb, const f16* __restrict__ Wf,
    const float* __restrict__ bias, const f16* __restrict__ Res,
    float* __restrict__ Yf, f16* __restrict__ Yb, f16* __restrict__ Pool,
    float2* __restrict__ Pmin, int pstride,
    int Cinp, int Cout, int lgT, int tapshift, int relu,
    int n0, int o0, int py, f16* Als, f16* Bls)
{
  const int tid  = threadIdx.x;
  const int wave = tid >> 6;
  const int lane = tid & 63;
  const int T  = 1 << lgT;
  const int b  = n0 >> lgT;
  const int t0 = n0 & (T - 1);

  const int lane4 = lane >> 2;  // row-within-16 for B staging
  // B pre-swizzle (both-sides): phys slot (lane&3) of LDS row r*16+lane4
  // holds global slot (lane&3)^((row>>1)&3) == (lane&3)^((lane>>3)&3).
  const int lkB = ((lane & 3) ^ ((lane >> 3) & 3)) << 3;
  const f16* gB0 = Xb + (size_t)(b * (T + 4) + t0) * Cinp + lkB;

  const int mB  = (wave & 1) * 64;
  const int nB  = (wave >> 1) * 64;
  const int r16 = lane & 15;
  const int g4  = lane >> 4;
  const int C32 = Cinp >> 5;
  const int OB  = Cout >> 4;
  const int fb  = (wave & 1) * 4;

  const f16* gW = Wf + (((size_t)(o0 >> 4)) << 9) + lane * 8;

  float4v acc[4][4] = {};

#pragma unroll 1
  for (int c32 = 0; c32 < C32; ++c32) {
    __syncthreads();  // previous iteration's LDS reads complete
#pragma unroll
    for (int r = wave; r < NTAP * 8; r += 4) {
      const int kt = r >> 3, frag = r & 7;
      async16(gW + (((size_t)((kt * C32 + c32) * OB) + frag) << 9),
              &Als[r * 512 + lane * 8]);
    }
    for (int r = wave; r < 9; r += 4)
      async16(gB0 + (size_t)(r * 16 + lane4) * Cinp + (c32 << 5),
              &Bls[r * 512 + lane * 8]);
    __syncthreads();  // drains vmcnt: staging visible

#pragma unroll
    for (int kt = 0; kt < NTAP; ++kt) {
      half8 af[4], bv[4];
#pragma unroll
      for (int i = 0; i < 4; ++i)
        af[i] = *(const half8*)&Als[(kt * 8 + fb + i) * 512 + lane * 8];
#pragma unroll
      for (int j = 0; j < 4; ++j) {
        const int row = nB + j * 16 + r16 + tapshift + kt;
        const int sl  = g4 ^ ((row >> 1) & 3);
        bv[j] = *(const half8*)&Bls[row * 32 + sl * 8];
      }
      __builtin_amdgcn_s_setprio(1);
#pragma unroll
      for (int i = 0; i < 4; ++i)
#pragma unroll
        for (int j = 0; j < 4; ++j)
          acc[i][j] = __builtin_amdgcn_mfma_f32_16x16x32_f16(af[i], bv[j], acc[i][j], 0, 0, 0);
      __builtin_amdgcn_s_setprio(0);
    }
  }

  // epilogue: D[row][col]: col = lane&15, row = (lane>>4)*4 + reg
  const int col = lane & 15;
  const int qr4 = (lane >> 4) << 2;

  if (Pmin) {
    // VQ: per-row argmin over this tile's 128 bins -> Pmin[n][pstride]
    float bv[4] = {3.4e38f, 3.4e38f, 3.4e38f, 3.4e38f};
    int   bi[4] = {0, 0, 0, 0};
#pragma unroll
    for (int i = 0; i < 4; ++i) {
      const int o = o0 + mB + i * 16 + qr4;
      const float4v bb = *(const float4v*)&bias[o];  // |c|^2
#pragma unroll
      for (int j = 0; j < 4; ++j) {
        float4v v = acc[i][j] + bb;
#pragma unroll
        for (int r = 0; r < 4; ++r) {
          const float f = v[r];
          const int id = o + r;
          if (f < bv[j] || (f == bv[j] && id < bi[j])) { bv[j] = f; bi[j] = id; }
        }
      }
    }
#pragma unroll
    for (int off = 32; off >= 16; off >>= 1)
#pragma unroll
      for (int j = 0; j < 4; ++j) {
        const float ov = __shfl_down(bv[j], off);
        const int   oi = __shfl_down(bi[j], off);
        if (ov < bv[j] || (ov == bv[j] && oi < bi[j])) { bv[j] = ov; bi[j] = oi; }
      }
    __syncthreads();  // LDS reads done -> reuse Als as candidate scratch
    float2* cand = (float2*)Als;  // [128 t][2 m-waves]
    if (lane < 16)
#pragma unroll
      for (int j = 0; j < 4; ++j)
        cand[(nB + j * 16 + lane) * 2 + (wave & 1)] =
            make_float2(bv[j], __int_as_float(bi[j]));
    __syncthreads();
    if (tid < 128) {
      float2 c0 = cand[tid * 2 + 0], c1 = cand[tid * 2 + 1];
      int i0 = __float_as_int(c0.x < c1.x ? c0.y : c1.y);
      float v0 = fminf(c0.x, c1.x);
      if (c0.x == c1.x) i0 = min(__float_as_int(c0.y), __float_as_int(c1.y));
      Pmin[(size_t)(n0 + tid) * pstride + py] =
          make_float2(v0, __int_as_float(i0));
    }
    return;
  }

  if (Pool) {
    // fused maxpool(8) over t: 8-lane shfl-max, write pooled rows only.
    const int TP4 = (T >> 3) + 4;  // pooled buffer rows incl. halo
#pragma unroll
    for (int i = 0; i < 4; ++i) {
      const int o = o0 + mB + i * 16 + qr4;
      const float4v bb = *(const float4v*)&bias[o];
#pragma unroll
      for (int j = 0; j < 4; ++j) {
        const int t = t0 + nB + j * 16 + col;
        float4v v = acc[i][j] + bb;
        if (relu) {
          v.x = fmaxf(v.x, 0.f); v.y = fmaxf(v.y, 0.f);
          v.z = fmaxf(v.z, 0.f); v.w = fmaxf(v.w, 0.f);
        }
        if (Res) {
          half4 r = *(const half4*)&Res[(size_t)(b * (T + 4) + t + 2) * Cout + o];
          v.x += (float)r.x; v.y += (float)r.y; v.z += (float)r.z; v.w += (float)r.w;
        }
#pragma unroll
        for (int s = 1; s < 8; s <<= 1) {
          v.x = fmaxf(v.x, __shfl_xor(v.x, s));
          v.y = fmaxf(v.y, __shfl_xor(v.y, s));
          v.z = fmaxf(v.z, __shfl_xor(v.z, s));
          v.w = fmaxf(v.w, __shfl_xor(v.w, s));
        }
        if ((col & 7) == 0) {
          const int tp = t >> 3;
          half4 h;
          h.x = (f16)v.x; h.y = (f16)v.y; h.z = (f16)v.z; h.w = (f16)v.w;
          *(half4*)&Pool[((size_t)(b * TP4 + tp + 2)) * Cout + o] = h;
        }
      }
    }
    return;
  }

#pragma unroll
  for (int i = 0; i < 4; ++i) {
    const int o = o0 + mB + i * 16 + qr4;
    const float4v bb = *(const float4v*)&bias[o];
#pragma unroll
    for (int j = 0; j < 4; ++j) {
      const int t = t0 + nB + j * 16 + col;
      float4v v = acc[i][j] + bb;
      if (relu) {
        v.x = fmaxf(v.x, 0.f); v.y = fmaxf(v.y, 0.f);
        v.z = fmaxf(v.z, 0.f); v.w = fmaxf(v.w, 0.f);
      }
      if (Res) {
        half4 r = *(const half4*)&Res[(size_t)(b * (T + 4) + t + 2) * Cout + o];
        v.x += (float)r.x; v.y += (float)r.y; v.z += (float)r.z; v.w += (float)r.w;
      }
      if (Yf) *(float4v*)&Yf[(size_t)(b * T + t) * Cout + o] = v;
      if (Yb) {
        half4 h;
        h.x = (f16)v.x; h.y = (f16)v.y; h.z = (f16)v.z; h.w = (f16)v.w;
        *(half4*)&Yb[(size_t)(b * (T + 4) + t + 2) * Cout + o] = h;
      }
    }
  }
}

template <int NTAP>
__global__ __launch_bounds__(256, 3) void conv_gemm(
    const f16* __restrict__ Xb, const f16* __restrict__ Wf,
    const float* __restrict__ bias, const f16* __restrict__ Res,
    float* __restrict__ Yf, f16* __restrict__ Yb, f16* __restrict__ Pool,
    float2* __restrict__ Pmin,
    int Cinp, int Cout, int lgT, int tapshift, int relu)
{
  __shared__ __align__(16) f16 Als[NTAP * 8 * 512];
  __shared__ __align__(16) f16 Bls[144 * 32];
  conv_tile<NTAP>(Xb, Wf, bias, Res, Yf, Yb, Pool, Pmin, (int)gridDim.y,
                  Cinp, Cout, lgT, tapshift, relu,
                  (int)(blockIdx.x << 7), (int)(blockIdx.y << 7),
                  (int)blockIdx.y, Als, Bls);
}

// ---------------------------------------------------------------------------
// merged preprocessing: halo zero + weight repacks + codebook + mel cast.
__device__ void repack_dev(const float* __restrict__ w, f16* __restrict__ wp,
                           int O, int I, int Ip, int l, int xb, int nxb)
{
  const int C8 = Ip >> 3;
  const int n = O * C8;
  const float* wl = w + (size_t)l * O * I * 5;
  f16* wpl = wp + (size_t)l * 5 * O * Ip;
  const int OB = O >> 4;
  for (int e = xb * 256 + threadIdx.x; e < n; e += nxb * 256) {
    const int o = e / C8, c8 = e - o * C8;
    const int ci0 = c8 << 3;
    const size_t base = ((((size_t)(ci0 >> 5) * OB + (o >> 4)) << 6)
                         + ((o & 15) | ((c8 & 3) << 4))) << 3;
    half8 hv[5];
#pragma unroll
    for (int kt = 0; kt < 5; ++kt)
#pragma unroll
      for (int u = 0; u < 8; ++u) hv[kt][u] = (f16)0.f;
    const int lim = (I - ci0 < 8) ? (I - ci0) : 8;
    for (int u = 0; u < lim; ++u) {
      const float* src = wl + ((size_t)o * I + ci0 + u) * 5;
#pragma unroll
      for (int kt = 0; kt < 5; ++kt) hv[kt][u] = (f16)src[kt];
    }
#pragma unroll
    for (int kt = 0; kt < 5; ++kt)
      *(half8*)&wpl[(size_t)kt * O * Ip + base] = hv[kt];
  }
}

__global__ void prep(const float* __restrict__ w_pre,
                     const float* __restrict__ w_b1,
                     const float* __restrict__ w_b2,
                     const float* __restrict__ w_post,
                     const float* __restrict__ cbk,
                     const float* __restrict__ mel,
                     f16* wpPre, f16* wpB1, f16* wpB2, f16* wpPost,
                     f16* wpCb, float* cnorm, f16* xmel,
                     f16* a0, f16* a1, f16* b0, f16* b1, f16* zb,
                     float* accum, int* cnt)
{
  const int bid = blockIdx.x;
  const int tid = threadIdx.x;
  if (bid == 0 && tid == 0) { accum[0] = 0.f; accum[1] = 0.f; *cnt = 0; }

  if (bid < 640) {                       // halo zero: 5 bufs * 32 b * 4 rows
    int buf = bid >> 7, r = bid & 127, bb = r >> 2, k = r & 3;
    f16* p; int T4, C;
    if      (buf == 0) { p = a0; T4 = 2052; C = 384; }
    else if (buf == 1) { p = a1; T4 = 2052; C = 384; }
    else if (buf == 2) { p = b0; T4 = 260;  C = 384; }
    else if (buf == 3) { p = b1; T4 = 260;  C = 384; }
    else               { p = zb; T4 = 260;  C = 256; }
    int tt = (k < 2) ? k : (T4 - 4 + k);
    f16* rowp = p + ((size_t)bb * T4 + tt) * C;
    for (int c = tid; c < C; c += 256) rowp[c] = (f16)0.f;
  } else if (bid < 1072) {               // B1 repack: 72 x 6 layers
    repack_dev(w_b1, wpB1, 384, 384, 384, (bid - 640) / 72, (bid - 640) % 72, 72);
  } else if (bid < 1504) {               // B2 repack
    repack_dev(w_b2, wpB2, 384, 384, 384, (bid - 1072) / 72, (bid - 1072) % 72, 72);
  } else if (bid < 1522) {               // pre repack: 18 blocks
    repack_dev(w_pre, wpPre, 384, 80, 96, 0, bid - 1504, 18);
  } else if (bid < 1570) {               // post repack: 48 blocks
    repack_dev(w_post, wpPost, 256, 384, 384, 0, bid - 1522, 48);
  } else if (bid < 1826) {               // codebook: 4 rows/block (wave each)
    int o = (bid - 1570) * 4 + (tid >> 6);
    int lane = tid & 63;
    float4v c = *(const float4v*)&cbk[(size_t)o * 256 + lane * 4];
    float s = c.x * c.x + c.y * c.y + c.z * c.z + c.w * c.w;
    for (int off = 32; off > 0; off >>= 1) s += __shfl_down(s, off);
    if (lane == 0) cnorm[o] = s;
#pragma unroll
    for (int u = 0; u < 4; ++u) {
      int ci  = lane * 4 + u;
      int c32 = ci >> 5;
      int fl  = (o & 15) + (((ci >> 3) & 3) << 4);
      int e   = ci & 7;
      wpCb[(((size_t)(c32 * 64 + (o >> 4)) << 6) + fl) * 8 + e] =
          (f16)(-2.f * c[u]);
    }
  } else {                               // mel -> f16 halo'd: 3078 blocks
    int idx = (bid - 1826) * 256 + tid;
    if (idx >= 32 * 2052 * 12) return;
    int c8 = idx % 12, r = idx / 12, tt = r % 2052, b = r / 2052;
    int t = tt - 2;
    bool trow = (t >= 0) && (t < 2048);
    half8 hv;
#pragma unroll
    for (int e = 0; e < 8; ++e) {
      int m = c8 * 8 + e;
      float v = (trow && m < 80) ? mel[((size_t)b * 2048 + t) * 80 + m] : 0.f;
      hv[e] = (f16)v;
    }
    *(half8*)&xmel[((size_t)b * 2052 + tt) * 96 + c8 * 8] = hv;
  }
}

// gather + loss, with finalize folded in via last-block-done counter.
__global__ void vq_gather(const float* __restrict__ zf,   // [8192][256]
                          const float* __restrict__ cb,   // [1024][256]
                          const float2* __restrict__ P,   // [8192][8]
                          float* __restrict__ zq,
                          float* __restrict__ accum, int* cnt,
                          float* __restrict__ out2)
{
  int row = blockIdx.x * 4 + (threadIdx.x >> 6);
  int lane = threadIdx.x & 63;
  float2 p = P[(size_t)row * 8 + (lane & 7)];
  float bv = p.x;
  int j = __float_as_int(p.y);
#pragma unroll
  for (int s = 1; s < 8; s <<= 1) {
    float ov = __shfl_xor(bv, s);
    int oi = __shfl_xor(j, s);
    if (ov < bv || (ov == bv && oi < j)) { bv = ov; j = oi; }
  }
  float4v z = *(const float4v*)&zf[(size_t)row * 256 + lane * 4];
  float4v q = *(const float4v*)&cb[(size_t)j * 256 + lane * 4];
  *(float4v*)&zq[(size_t)row * 256 + lane * 4] = q;
  float4v d = z - q;
  float s = d.x * d.x + d.y * d.y + d.z * d.z + d.w * d.w;
  for (int off = 32; off > 0; off >>= 1) s += __shfl_down(s, off);
  if (lane == 0) atomicAdd(accum, s);
  __syncthreads();  // vmcnt(0) drain: this block's atomics issued & complete
  if (threadIdx.x == 0) {
    int done = __hip_atomic_fetch_add(cnt, 1, __ATOMIC_ACQ_REL,
                                      __HIP_MEMORY_SCOPE_AGENT);
    if (done == 2047) {  // last block: all accum adds visible (acquire)
      float c = __hip_atomic_load(accum, __ATOMIC_ACQUIRE,
                                  __HIP_MEMORY_SCOPE_AGENT)
                * (1.0f / 2097152.0f);
      out2[0] = c;
      out2[1] = c;
    }
  }
}

// ---------------------------------------------------------------------------
extern "C" void kernel_launch(void* const* d_in, const int* in_sizes, int n_in,
                              void* d_out, int out_size, void* d_ws, size_t ws_size,
                              hipStream_t stream)
{
  (void)in_sizes; (void)n_in; (void)out_size;
  const float* mel    = (const float*)d_in[0];
  const float* w_pre  = (const float*)d_in[1];
  const float* b_pre  = (const float*)d_in[2];
  const float* w_b1   = (const float*)d_in[3];
  const float* b_b1   = (const float*)d_in[4];
  const float* w_b2   = (const float*)d_in[5];
  const float* b_b2   = (const float*)d_in[6];
  const float* w_post = (const float*)d_in[7];
  const float* b_post = (const float*)d_in[8];
  const float* cbk    = (const float*)d_in[9];
  float* out = (float*)d_out;

  size_t off = 0;
  auto carve = [&](size_t bytes) -> char* {
    char* p = (char*)d_ws + off;
    off += (bytes + 255) & ~(size_t)255;
    return p;
  };
  f16*   wpPre  = (f16*)carve((size_t)5 * 384 * 96 * 2);
  f16*   wpB1   = (f16*)carve((size_t)6 * 5 * 384 * 384 * 2);
  f16*   wpB2   = (f16*)carve((size_t)6 * 5 * 384 * 384 * 2);
  f16*   wpPost = (f16*)carve((size_t)5 * 256 * 384 * 2);
  f16*   wpCb   = (f16*)carve((size_t)1024 * 256 * 2);
  float* cnorm  = (float*)carve(1024 * 4);
  float* accum  = (float*)carve(256);
  int*   cnt    = (int*)carve(256);
  f16*   xmel   = (f16*)carve((size_t)32 * 2052 * 96 * 2);
  f16*   xa0    = (f16*)carve((size_t)32 * 2052 * 384 * 2);
  f16*   xa1    = (f16*)carve((size_t)32 * 2052 * 384 * 2);
  f16*   xb0    = (f16*)carve((size_t)32 * 260 * 384 * 2);
  f16*   xb1    = (f16*)carve((size_t)32 * 260 * 384 * 2);
  f16*   zeb    = (f16*)carve((size_t)32 * 260 * 256 * 2);
  float* zf     = (float*)carve((size_t)32 * 256 * 256 * 4);
  float2* part  = (float2*)carve((size_t)8192 * 8 * 8);
  carve(131072);  // guard: B staging over-reads past last buffer
  if (off > ws_size) return;  // ~152 MB needed

  prep<<<4904, 256, 0, stream>>>(w_pre, w_b1, w_b2, w_post, cbk, mel,
                                 wpPre, wpB1, wpB2, wpPost, wpCb, cnorm, xmel,
                                 xa0, xa1, xb0, xb1, zeb, accum, cnt);

  auto conv5 = [&](const f16* X, const f16* W, const float* bia, const f16* R,
                   float* YF, f16* YB, f16* PL, int Cinp, int Cout, int lgT,
                   int relu) {
    dim3 g((32 << lgT) >> 7, Cout >> 7);
    conv_gemm<5><<<g, 256, 0, stream>>>(X, W, bia, R, YF, YB, PL, nullptr,
                                        Cinp, Cout, lgT, 0, relu);
  };

  // pre-conv: relu(conv(mel))
  conv5(xmel, wpPre, b_pre, nullptr, nullptr, xa0, nullptr, 96, 384, 11, 1);
  // stack 1 @ T=2048 (last layer fuses maxpool(8) -> xb0)
  for (int i = 0; i < 5; ++i) {
    f16* in = (i & 1) ? xa1 : xa0;
    f16* o_ = (i & 1) ? xa0 : xa1;
    conv5(in, wpB1 + (size_t)i * 5 * 384 * 384, b_b1 + i * 384, in,
          nullptr, o_, nullptr, 384, 384, 11, 1);
  }
  conv5(xa1, wpB1 + (size_t)5 * 5 * 384 * 384, b_b1 + 5 * 384, xa1,
        nullptr, nullptr, xb0, 384, 384, 11, 1);
  // stack 2 @ T=256 (separate launches; persistent fusion regressed in R11)
  for (int i = 0; i < 6; ++i) {
    f16* in = (i & 1) ? xb1 : xb0;
    f16* o_ = (i & 1) ? xb0 : xb1;
    conv5(in, wpB2 + (size_t)i * 5 * 384 * 384, b_b2 + i * 384, in,
          nullptr, o_, nullptr, 384, 384, 8, 1);
  }
  // post-conv: ze (f32 for loss, f16+halo for VQ scores)
  conv5(xb0, wpPost, b_post, nullptr, zf, zeb, nullptr, 384, 256, 8, 0);
  // VQ scores: |c|^2 - 2 z.c as 1-tap "conv" + fused per-tile argmin
  {
    dim3 g((32 * 256) >> 7, 1024 >> 7);
    conv_gemm<1><<<g, 256, 0, stream>>>(zeb, wpCb, cnorm, nullptr, nullptr,
                                        nullptr, nullptr, part,
                                        256, 1024, 8, 2, 0);
  }
  // gather + losses (finalize folded via last-block counter)
  vq_gather<<<2048, 256, 0, stream>>>(zf, cbk, part, out, accum, cnt,
                                      out + 2097152);
}